// Round 13
// baseline (613.827 us; speedup 1.0000x reference)
//
#include <hip/hip_runtime.h>
#include <math.h>

#define N_NODES 100000
#define D_IN    1000
#define D_OUT   20
#define N_HEAD  8
#define C_ONE   8
#define SCAN_CHUNK 512
#define NCH ((N_NODES + SCAN_CHUNK - 1) / SCAN_CHUNK)

// GEMM1 tiling
#define BM 128
#define BN 64
#define BK 64
#define KPAD 1024
#define KTILES 16
#define G1_BLOCKS ((N_NODES + BM - 1) / BM)   // 782
#define BN_BLOCKS 500                          // 200 rows each, atomic-free partials
#define NPART BN_BLOCKS
#define PREP_BLOCKS 298

static constexpr float kBnEps = 1e-5f;
static constexpr float kSlope = 0.2f;

typedef __attribute__((ext_vector_type(8))) short short8;
typedef __attribute__((ext_vector_type(4))) short sh4;
typedef __attribute__((ext_vector_type(4))) float f32x4;

__device__ __forceinline__ unsigned short f2bf(float f) {
    unsigned u = __float_as_uint(f);
    unsigned r = (u + 0x7fffu + ((u >> 16) & 1u)) >> 16;  // RNE
    return (unsigned short)r;
}
__device__ __forceinline__ float bf2f(short s) {
    unsigned u = ((unsigned)(unsigned short)s) << 16;
    return __uint_as_float(u);
}

// ===== phase1: BN partial stats, NO atomics (blocks [0,500)) ∪ degree count (rest) =====
__global__ __launch_bounds__(256) void k_phase1(const float* __restrict__ x,
                                                float* __restrict__ ps,   // [500][2][1000]
                                                const int* __restrict__ ei,
                                                int E, int TE,
                                                int* __restrict__ deg) {
    int b = blockIdx.x, tid = threadIdx.x;
    if (b < BN_BLOCKS) {
        int c4 = tid;
        if (c4 >= 250) return;
        int r0 = b * 200;
        float4 s = make_float4(0.f, 0.f, 0.f, 0.f);
        float4 q = make_float4(0.f, 0.f, 0.f, 0.f);
        const char* base = (const char*)x + (size_t)r0 * (D_IN * 4) + (size_t)c4 * 16;
        for (int i = 0; i < 200; i += 8) {
            float4 v[8];
            #pragma unroll
            for (int j = 0; j < 8; ++j)
                v[j] = *(const float4*)(base + (size_t)(i + j) * (D_IN * 4));
            #pragma unroll
            for (int j = 0; j < 8; ++j) {
                s.x += v[j].x; s.y += v[j].y; s.z += v[j].z; s.w += v[j].w;
                q.x += v[j].x * v[j].x; q.y += v[j].y * v[j].y;
                q.z += v[j].z * v[j].z; q.w += v[j].w * v[j].w;
            }
        }
        *(float4*)(ps + (size_t)b * 2000 + c4 * 4) = s;
        *(float4*)(ps + (size_t)b * 2000 + 1000 + c4 * 4) = q;
    } else {
        int eid = (b - BN_BLOCKS) * 256 + tid;
        if (eid >= TE) return;
        int dst = (eid < E) ? ei[E + eid] : (eid - E);
        atomicAdd(&deg[dst], 1);
    }
}

// ===== reduce partials -> cs/cs2 (40 blocks: 4 col-groups x 10 part-chunks) =====
__global__ void k_reduce(const float* __restrict__ ps,
                         float* __restrict__ cs, float* __restrict__ cs2) {
    int cg = blockIdx.x & 3;
    int ch = blockIdx.x >> 2;      // 0..9
    int c = cg * 256 + threadIdx.x;
    if (c >= D_IN) return;
    int b0 = ch * (NPART / 10), b1 = b0 + (NPART / 10);
    float s = 0.f, s2 = 0.f;
    #pragma unroll 5
    for (int b = b0; b < b1; ++b) {
        s  += ps[(size_t)b * 2000 + c];
        s2 += ps[(size_t)b * 2000 + 1000 + c];
    }
    atomicAdd(&cs[c], s);
    atomicAdd(&cs2[c], s2);
}

// ===== phase2: scan_a (blocks [0,NCH)) ∪ weight prep (rest) =====
// prep blocks: [0,256) W1t, [256,296) W2t, 296 c1, 297 wt_s/wt_d
__global__ void k_phase2(const int* __restrict__ deg, int* __restrict__ csum,
                         const float* __restrict__ W1, const float* __restrict__ W2,
                         const float* __restrict__ cs, const float* __restrict__ cs2,
                         const float* __restrict__ gamma, const float* __restrict__ beta,
                         const float* __restrict__ a_src2, const float* __restrict__ a_dst2,
                         short* __restrict__ W1t, short* __restrict__ W2t,
                         float* __restrict__ c1,
                         float* __restrict__ wt_s, float* __restrict__ wt_d) {
    __shared__ int red[4];
    __shared__ float part[4][64];
    int b = blockIdx.x, tid = threadIdx.x;
    if (b < NCH) {
        int i0 = b * SCAN_CHUNK + tid * 2;
        int a = (i0 < N_NODES) ? deg[i0] : 0;
        int bb = (i0 + 1 < N_NODES) ? deg[i0 + 1] : 0;
        int t = a + bb;
        #pragma unroll
        for (int d = 1; d < 64; d <<= 1) t += __shfl_xor(t, d);
        if ((tid & 63) == 0) red[tid >> 6] = t;
        __syncthreads();
        if (tid == 0) csum[b] = red[0] + red[1] + red[2] + red[3];
        return;
    }
    int pb = b - NCH;
    if (pb < 256) {
        int idx = pb * 256 + tid;                 // 64*KPAD = 65536
        int n = idx >> 10, k = idx & (KPAD - 1);
        float v = 0.f;
        if (k < D_IN) {
            float mu  = cs[k]  * (1.f / N_NODES);
            float var = cs2[k] * (1.f / N_NODES) - mu * mu;
            float sc  = rsqrtf(var + kBnEps) * gamma[k];
            v = W1[k * 64 + n] * sc;
        }
        W1t[idx] = (short)f2bf(v);
    } else if (pb < 296) {
        int idx = (pb - 256) * 256 + tid;         // 160*64 = 10240
        if (idx < 160 * 64) {
            int n = idx >> 6, k = idx & 63;
            W2t[idx] = (short)f2bf(W2[k * 160 + n]);
        }
    } else if (pb == 296) {
        int j  = tid & 63;
        int kc = tid >> 6;
        float acc = 0.f;
        for (int k = kc * 250; k < (kc + 1) * 250; ++k) {
            float mu  = cs[k]  * (1.f / N_NODES);
            float var = cs2[k] * (1.f / N_NODES) - mu * mu;
            float sc  = rsqrtf(var + kBnEps) * gamma[k];
            float sh  = beta[k] - mu * sc;
            acc += sh * W1[k * 64 + j];
        }
        part[kc][j] = acc;
        __syncthreads();
        if (kc == 0) c1[j] = part[0][j] + part[1][j] + part[2][j] + part[3][j];
    } else {
        // wt_s[h][k] = sum_c W2[k][h*20+c]*a_src2[h][c]; wt_d likewise
        #pragma unroll
        for (int it = 0; it < 2; ++it) {
            int idx = it * 256 + tid;             // 512 = 8h x 64k
            int h = idx >> 6, k = idx & 63;
            float ss = 0.f, dd = 0.f;
            #pragma unroll
            for (int c = 0; c < 20; ++c) {
                float w = W2[k * 160 + h * 20 + c];
                ss += w * a_src2[h * 20 + c];
                dd += w * a_dst2[h * 20 + c];
            }
            wt_s[h * 64 + k] = ss;
            wt_d[h * 64 + k] = dd;
        }
    }
}

// ===== phase3: scan_c (chunk base self-computed) =====
__global__ void k_scan_c(const int* __restrict__ deg, const int* __restrict__ csum,
                         int TE, int* __restrict__ row_start, int* __restrict__ cursor) {
    __shared__ int wsum1[4];
    __shared__ int wsum2[4];
    __shared__ int base_sh;
    int c = blockIdx.x, tid = threadIdx.x;
    int lane = tid & 63, w = tid >> 6;

    int pv = (tid < c) ? csum[tid] : 0;   // NCH <= 256
    #pragma unroll
    for (int d = 1; d < 64; d <<= 1) pv += __shfl_xor(pv, d);
    if (lane == 0) wsum1[w] = pv;
    __syncthreads();
    if (tid == 0) base_sh = wsum1[0] + wsum1[1] + wsum1[2] + wsum1[3];

    int i0 = c * SCAN_CHUNK + tid * 2;
    int a = (i0 < N_NODES) ? deg[i0] : 0;
    int b = (i0 + 1 < N_NODES) ? deg[i0 + 1] : 0;
    int t = a + b;
    int incl = t;
    #pragma unroll
    for (int d = 1; d < 64; d <<= 1) {
        int v = __shfl_up(incl, d);
        if (lane >= d) incl += v;
    }
    if (lane == 63) wsum2[w] = incl;
    __syncthreads();
    int wbase = 0;
    for (int k = 0; k < w; ++k) wbase += wsum2[k];
    int ex = base_sh + wbase + incl - t;
    if (i0 < N_NODES)     { row_start[i0] = ex;         cursor[i0] = ex; }
    if (i0 + 1 < N_NODES) { row_start[i0 + 1] = ex + a; cursor[i0 + 1] = ex + a; }
    if (c == 0 && tid == 0) row_start[N_NODES] = TE;
}

// ===== phase4: gemm1+att1 (blocks [0,G1_BLOCKS)) ∪ CSR fill (rest) =====
__global__ __launch_bounds__(256) void k_phase4(const float* __restrict__ x,
                                                const short* __restrict__ W1t,
                                                const float* __restrict__ c1,
                                                const float* __restrict__ a_src1,
                                                const float* __restrict__ a_dst1,
                                                short* __restrict__ h1b,
                                                float* __restrict__ als,
                                                float* __restrict__ ald,
                                                const int* __restrict__ ei,
                                                int E, int TE,
                                                int* __restrict__ cursor,
                                                int* __restrict__ srcs) {
    __shared__ short lA[BM * BK];
    __shared__ short lB[BN * BK];

    int tid = threadIdx.x;
    if ((int)blockIdx.x >= G1_BLOCKS) {
        int eid = ((int)blockIdx.x - G1_BLOCKS) * 256 + tid;
        if (eid < TE) {
            int src, dst;
            if (eid < E) { src = ei[eid]; dst = ei[E + eid]; }
            else { src = eid - E; dst = src; }
            int pos = atomicAdd(&cursor[dst], 1);
            srcs[pos] = src;
        }
        return;
    }

    int lane = tid & 63;
    int wave = tid >> 6;
    int l15  = lane & 15, kq = lane >> 4;
    int row0 = blockIdx.x * BM;
    int wm0  = wave * 32;

    f32x4 zero4 = {0.f, 0.f, 0.f, 0.f};
    f32x4 acc[2][4];
    #pragma unroll
    for (int m = 0; m < 2; ++m)
        #pragma unroll
        for (int n = 0; n < 4; ++n) acc[m][n] = zero4;

    int ar = tid >> 4;
    int akf4 = tid & 15;

    for (int kt = 0; kt < KTILES; ++kt) {
        int k0 = kt * BK;
        bool kok = (k0 + akf4 * 4) < D_IN;
        #pragma unroll
        for (int p = 0; p < 8; ++p) {
            int r = ar + p * 16;
            int gr = row0 + r;
            float4 v = make_float4(0.f, 0.f, 0.f, 0.f);
            if (gr < N_NODES && kok)
                v = *(const float4*)(x + (size_t)gr * D_IN + k0 + akf4 * 4);
            unsigned lo = f2bf(v.x) | ((unsigned)f2bf(v.y) << 16);
            unsigned hi = f2bf(v.z) | ((unsigned)f2bf(v.w) << 16);
            int off = r * 128 + ((((akf4 >> 1) ^ (r & 7)) << 4) | ((akf4 & 1) << 3));
            *(uint2*)((char*)lA + off) = make_uint2(lo, hi);
        }
        #pragma unroll
        for (int c = tid; c < 512; c += 256) {
            int n = c >> 3, s = c & 7;
            short8 v = *(const short8*)((const char*)W1t + n * (KPAD * 2) + k0 * 2 + (s << 4));
            int off = n * 128 + ((s ^ (n & 7)) << 4);
            *(short8*)((char*)lB + off) = v;
        }
        __syncthreads();
        #pragma unroll
        for (int h = 0; h < 2; ++h) {
            short8 aF[2], bF[4];
            #pragma unroll
            for (int m = 0; m < 2; ++m) {
                int row = wm0 + m * 16 + l15;
                int off = row * 128 + (((((h << 2) + kq)) ^ (row & 7)) << 4);
                aF[m] = *(const short8*)((const char*)lA + off);
            }
            #pragma unroll
            for (int n = 0; n < 4; ++n) {
                int col = n * 16 + l15;
                int off = col * 128 + (((((h << 2) + kq)) ^ (col & 7)) << 4);
                bF[n] = *(const short8*)((const char*)lB + off);
            }
            #pragma unroll
            for (int m = 0; m < 2; ++m)
                #pragma unroll
                for (int n = 0; n < 4; ++n)
                    acc[m][n] = __builtin_amdgcn_mfma_f32_16x16x32_bf16(aF[m], bF[n], acc[m][n], 0, 0, 0);
        }
        __syncthreads();
    }

    float cv[4];
    #pragma unroll
    for (int n = 0; n < 4; ++n) cv[n] = c1[n * 16 + l15];
    #pragma unroll
    for (int m = 0; m < 2; ++m)
        #pragma unroll
        for (int q = 0; q < 4; ++q) {
            int rl = wm0 + m * 16 + (kq << 2) + q;
            #pragma unroll
            for (int n = 0; n < 4; ++n)
                lA[rl * 64 + n * 16 + l15] = (short)f2bf(acc[m][n][q] + cv[n]);
        }
    __syncthreads();
    #pragma unroll
    for (int idx = tid; idx < 1024; idx += 256) {
        int r = idx >> 3, s = idx & 7;
        int gr = row0 + r;
        if (gr < N_NODES)
            *(short8*)((char*)h1b + (size_t)gr * 128 + (s << 4)) =
                *(const short8*)((const char*)lA + r * 128 + (s << 4));
    }
    #pragma unroll
    for (int pair = tid; pair < 1024; pair += 256) {
        int r = pair >> 3, hd = pair & 7;
        int gr = row0 + r;
        if (gr >= N_NODES) continue;
        short8 v = *(const short8*)((const char*)lA + r * 128 + hd * 16);
        float s = 0.f, d = 0.f;
        #pragma unroll
        for (int c = 0; c < 8; ++c) {
            float f = bf2f(v[c]);
            s += f * a_src1[hd * 8 + c];
            d += f * a_dst1[hd * 8 + c];
        }
        als[gr * 8 + hd] = s;
        ald[gr * 8 + hd] = d;
    }
}

// ====== FUSED layer-2 front: gather1 -> out1 LDS tile -> out1b + als2/ald2 via w-tilde ======
__global__ __launch_bounds__(512) void k_fused_l2(const int* __restrict__ row_start,
                                                  const int* __restrict__ srcs,
                                                  const float* __restrict__ als1,
                                                  const float* __restrict__ ald1,
                                                  const short* __restrict__ h1b,
                                                  const float* __restrict__ b1,
                                                  const float* __restrict__ wt_s,
                                                  const float* __restrict__ wt_d,
                                                  short* __restrict__ out1b,
                                                  float* __restrict__ als2,
                                                  float* __restrict__ ald2) {
    __shared__ short lA[128 * 64];   // swizzled out1 tile (16 KB)
    __shared__ float lWs[512];       // wt_s
    __shared__ float lWd[512];       // wt_d

    int tid  = threadIdx.x;
    int row0 = blockIdx.x * 128;

    if (tid < 512) { lWs[tid] = wt_s[tid]; lWd[tid] = wt_d[tid]; }

    // gather phase: 1024 (row,head) pairs, 2 per thread; max-free online softmax
    #pragma unroll
    for (int pp = 0; pp < 2; ++pp) {
        int pair = tid + pp * 512;
        int r = pair >> 3, hd = pair & 7;
        int dst = row0 + r;
        short8 o = {0, 0, 0, 0, 0, 0, 0, 0};
        if (dst < N_NODES) {
            int beg = row_start[dst], end = row_start[dst + 1];
            float ad = ald1[dst * 8 + hd];
            float sum = 0.f;
            float acc[C_ONE] = {};
            for (int e = beg; e < end; ++e) {
                int s = srcs[e];
                float v = als1[s * 8 + hd] + ad;
                v = v >= 0.f ? v : kSlope * v;
                float wgt = __expf(v);
                short8 hv = *(const short8*)((const char*)h1b + (size_t)s * 128 + hd * 16);
                sum += wgt;
                #pragma unroll
                for (int c = 0; c < C_ONE; ++c) acc[c] += wgt * bf2f(hv[c]);
            }
            float inv = 1.f / (sum + 1e-16f);
            #pragma unroll
            for (int c = 0; c < C_ONE; ++c) {
                float v = acc[c] * inv + b1[hd * 8 + c];
                v = v > 0.f ? v : __expf(v) - 1.f;
                o[c] = (short)f2bf(v);
            }
        }
        int off = r * 128 + ((hd ^ (r & 7)) << 4);
        *(short8*)((char*)lA + off) = o;
    }
    __syncthreads();

    // out1b store (de-swizzle), 1024 chunks
    #pragma unroll
    for (int pp = 0; pp < 2; ++pp) {
        int idx = tid + pp * 512;
        int r = idx >> 3, s = idx & 7;
        int gr = row0 + r;
        if (gr < N_NODES)
            *(short8*)((char*)out1b + (size_t)gr * 128 + (s << 4)) =
                *(const short8*)((const char*)lA + r * 128 + ((s ^ (r & 7)) << 4));
    }

    // als2/ald2 = out1[r] . wt_s/wt_d[hd]  (64-dim dots from LDS)
    #pragma unroll
    for (int pp = 0; pp < 2; ++pp) {
        int pair = tid + pp * 512;
        int r = pair >> 3, hd = pair & 7;
        int dst = row0 + r;
        if (dst >= N_NODES) continue;
        float s = 0.f, d = 0.f;
        #pragma unroll
        for (int ch = 0; ch < 8; ++ch) {
            short8 v = *(const short8*)((const char*)lA + r * 128 + ((ch ^ (r & 7)) << 4));
            #pragma unroll
            for (int c = 0; c < 8; ++c) {
                float f = bf2f(v[c]);
                s += f * lWs[hd * 64 + ch * 8 + c];
                d += f * lWd[hd * 64 + ch * 8 + c];
            }
        }
        als2[dst * 8 + hd] = s;
        ald2[dst * 8 + hd] = d;
    }
}

// ====== layer-2 gather in out1-space: 8 threads/dst (lane j = dims 8j..8j+8 + head j's alpha),
//        then per-head matvec with W2t (L1-resident), head-mean, bias, log_softmax ======
__global__ __launch_bounds__(256) void k_gather2(const int* __restrict__ row_start,
                                                 const int* __restrict__ srcs,
                                                 const float* __restrict__ als,
                                                 const float* __restrict__ ald,
                                                 const short* __restrict__ out1b,
                                                 const short* __restrict__ W2t,
                                                 const float* __restrict__ b2,
                                                 float* __restrict__ out) {
    int tid = threadIdx.x;
    int g = tid >> 3, j = tid & 7;
    int dst = blockIdx.x * 32 + g;
    if (dst >= N_NODES) return;

    int beg = row_start[dst], end = row_start[dst + 1];
    float adj = ald[dst * 8 + j];
    float Agg[8][8] = {};
    float mysum = 0.f;

    for (int e = beg; e < end; ++e) {
        int s = srcs[e];
        float v = als[s * 8 + j] + adj;
        v = v >= 0.f ? v : kSlope * v;
        float w = __expf(v);
        mysum += w;
        // broadcast alpha within 8-lane group: a_m = alpha of head (j^m)
        float a0 = w;
        float a1 = __shfl_xor(a0, 1);
        float a2 = __shfl_xor(a0, 2);
        float a3 = __shfl_xor(a1, 2);
        float a4 = __shfl_xor(a0, 4);
        float a5 = __shfl_xor(a1, 4);
        float a6 = __shfl_xor(a2, 4);
        float a7 = __shfl_xor(a3, 4);
        short8 hv = *(const short8*)((const char*)out1b + (size_t)s * 128 + j * 16);
        float f[8];
        #pragma unroll
        for (int c = 0; c < 8; ++c) f[c] = bf2f(hv[c]);
        #pragma unroll
        for (int c = 0; c < 8; ++c) {
            Agg[0][c] += a0 * f[c];
            Agg[1][c] += a1 * f[c];
            Agg[2][c] += a2 * f[c];
            Agg[3][c] += a3 * f[c];
            Agg[4][c] += a4 * f[c];
            Agg[5][c] += a5 * f[c];
            Agg[6][c] += a6 * f[c];
            Agg[7][c] += a7 * f[c];
        }
    }

    // collect denominators: S_m = sum of head (j^m)
    float s0 = mysum;
    float s1 = __shfl_xor(s0, 1);
    float s2 = __shfl_xor(s0, 2);
    float s3 = __shfl_xor(s1, 2);
    float s4 = __shfl_xor(s0, 4);
    float s5 = __shfl_xor(s1, 4);
    float s6 = __shfl_xor(s2, 4);
    float s7 = __shfl_xor(s3, 4);
    float iS[8];
    iS[0] = 1.f / (s0 + 1e-16f); iS[1] = 1.f / (s1 + 1e-16f);
    iS[2] = 1.f / (s2 + 1e-16f); iS[3] = 1.f / (s3 + 1e-16f);
    iS[4] = 1.f / (s4 + 1e-16f); iS[5] = 1.f / (s5 + 1e-16f);
    iS[6] = 1.f / (s6 + 1e-16f); iS[7] = 1.f / (s7 + 1e-16f);

    // epilogue: vals[c] = (1/8) sum_h sum_k (Agg_h[k]/S_h) * W2[k][h*20+c] + b2[c]
    // lane j holds k in [8j,8j+8); W2t[n][k] bf16 (L1-resident 20 KB)
    float vals[D_OUT];
    #pragma unroll
    for (int c = 0; c < D_OUT; ++c) {
        float pv = 0.f;
        #pragma unroll
        for (int m = 0; m < 8; ++m) {
            int h = j ^ m;
            short8 wv = *(const short8*)((const char*)W2t + (((h * 20 + c) << 6) + (j << 3)) * 2);
            float dot = 0.f;
            #pragma unroll
            for (int k = 0; k < 8; ++k) dot += Agg[m][k] * bf2f(wv[k]);
            pv += iS[m] * dot;
        }
        pv += __shfl_xor(pv, 1);
        pv += __shfl_xor(pv, 2);
        pv += __shfl_xor(pv, 4);
        vals[c] = 0.125f * pv + b2[c];
    }
    if (j == 0) {
        float mx = -1e30f;
        #pragma unroll
        for (int c = 0; c < D_OUT; ++c) mx = fmaxf(mx, vals[c]);
        float ssum = 0.f;
        #pragma unroll
        for (int c = 0; c < D_OUT; ++c) ssum += __expf(vals[c] - mx);
        float lse = mx + __logf(ssum);
        float* op = out + (size_t)dst * D_OUT;
        #pragma unroll
        for (int c = 0; c < D_OUT; ++c) op[c] = vals[c] - lse;
    }
}

extern "C" void kernel_launch(void* const* d_in, const int* in_sizes, int n_in,
                              void* d_out, int out_size, void* d_ws, size_t ws_size,
                              hipStream_t stream) {
    const float* x      = (const float*)d_in[0];
    const int*   ei     = (const int*)d_in[1];
    const float* gamma  = (const float*)d_in[2];
    const float* beta   = (const float*)d_in[3];
    const float* W1     = (const float*)d_in[4];
    const float* a_src1 = (const float*)d_in[5];
    const float* a_dst1 = (const float*)d_in[6];
    const float* b1     = (const float*)d_in[7];
    const float* W2     = (const float*)d_in[8];
    const float* a_src2 = (const float*)d_in[9];
    const float* a_dst2 = (const float*)d_in[10];
    const float* b2     = (const float*)d_in[11];
    float* out = (float*)d_out;
    (void)n_in; (void)out_size; (void)ws_size;

    const int E  = in_sizes[1] / 2;
    const int TE = E + N_NODES;

    char* wsb = (char*)d_ws;
    size_t off = 0;
    auto alloc = [&](size_t bytes) -> void* {
        void* p = wsb + off;
        off += (bytes + 255) & ~(size_t)255;
        return p;
    };
    float* cs    = (float*)alloc(D_IN * sizeof(float));   // adjacent to cs2 (one memset)
    float* cs2   = (float*)alloc(D_IN * sizeof(float));
    float* ps    = (float*)alloc((size_t)NPART * 2000 * sizeof(float));  // 4 MB partials
    short* W1t   = (short*)alloc((size_t)64 * KPAD * sizeof(short));
    short* W2t   = (short*)alloc((size_t)160 * 64 * sizeof(short));
    float* c1    = (float*)alloc(64 * sizeof(float));
    float* wts   = (float*)alloc(512 * sizeof(float));
    float* wtd   = (float*)alloc(512 * sizeof(float));
    short* h1b   = (short*)alloc((size_t)N_NODES * 64 * sizeof(short));
    short* out1b = (short*)alloc((size_t)N_NODES * 64 * sizeof(short));
    float* als   = (float*)alloc((size_t)N_NODES * N_HEAD * sizeof(float));
    float* ald   = (float*)alloc((size_t)N_NODES * N_HEAD * sizeof(float));
    float* als2  = (float*)alloc((size_t)N_NODES * N_HEAD * sizeof(float));
    float* ald2  = (float*)alloc((size_t)N_NODES * N_HEAD * sizeof(float));
    int*   deg   = (int*)alloc((size_t)N_NODES * sizeof(int));
    int*   rs    = (int*)alloc((size_t)(N_NODES + 1) * sizeof(int));
    int*   cur   = (int*)alloc((size_t)N_NODES * sizeof(int));
    int*   csum  = (int*)alloc((size_t)NCH * sizeof(int));
    int*   srcs  = (int*)alloc((size_t)TE * sizeof(int));

    int egrid = (TE + 255) / 256;

    hipMemsetAsync(deg, 0, (size_t)N_NODES * sizeof(int), stream);
    hipMemsetAsync(cs, 0, 8192, stream);

    // phase1: BN partial stats (atomic-free) ∪ degree histogram
    k_phase1<<<BN_BLOCKS + egrid, 256, 0, stream>>>(x, ps, ei, E, TE, deg);

    // reduce partials -> cs/cs2
    k_reduce<<<40, 256, 0, stream>>>(ps, cs, cs2);

    // phase2: scan_a ∪ weight prep (BN finalize + w-tilde inline)
    k_phase2<<<NCH + PREP_BLOCKS, 256, 0, stream>>>(deg, csum, W1, W2, cs, cs2,
                                                     gamma, beta, a_src2, a_dst2,
                                                     W1t, W2t, c1, wts, wtd);

    // phase3: row_start/cursor
    k_scan_c<<<NCH, 256, 0, stream>>>(deg, csum, TE, rs, cur);

    // phase4: gemm1+att1 ∪ CSR fill
    k_phase4<<<G1_BLOCKS + egrid, 256, 0, stream>>>(x, W1t, c1, a_src1, a_dst1,
                                                     h1b, als, ald, ei, E, TE, cur, srcs);

    // fused gather1 -> out1b + als2/ald2 (no gemm2, no h2b)
    k_fused_l2<<<(N_NODES + 127) / 128, 512, 0, stream>>>(rs, srcs, als, ald, h1b, b1,
                                                           wts, wtd, out1b, als2, ald2);

    // layer-2 gather in out1-space + transform + output
    k_gather2<<<(N_NODES + 31) / 32, 256, 0, stream>>>(rs, srcs, als2, ald2,
                                                        out1b, W2t, b2, out);
}

// Round 14
// 460.769 us; speedup vs baseline: 1.3322x; 1.3322x over previous
//
#include <hip/hip_runtime.h>
#include <math.h>

#define N_NODES 100000
#define D_IN    1000
#define D_OUT   20
#define N_HEAD  8
#define C_ONE   8
#define SCAN_CHUNK 512
#define NCH ((N_NODES + SCAN_CHUNK - 1) / SCAN_CHUNK)

// GEMM1 tiling
#define BM 128
#define BN 64
#define BK 64
#define KPAD 1024
#define KTILES 16
#define G1_BLOCKS ((N_NODES + BM - 1) / BM)   // 782
#define BN_BLOCKS 500                          // 200 rows each, atomic-free partials
#define NPART BN_BLOCKS
#define PREP_BLOCKS 297

static constexpr float kBnEps = 1e-5f;
static constexpr float kSlope = 0.2f;

typedef __attribute__((ext_vector_type(8))) short short8;
typedef __attribute__((ext_vector_type(4))) short sh4;
typedef __attribute__((ext_vector_type(4))) float f32x4;

__device__ __forceinline__ unsigned short f2bf(float f) {
    unsigned u = __float_as_uint(f);
    unsigned r = (u + 0x7fffu + ((u >> 16) & 1u)) >> 16;  // RNE
    return (unsigned short)r;
}
__device__ __forceinline__ float bf2f(short s) {
    unsigned u = ((unsigned)(unsigned short)s) << 16;
    return __uint_as_float(u);
}

// ===== phase1: BN partial stats, NO atomics (blocks [0,500)) ∪ degree count (rest) =====
__global__ __launch_bounds__(256) void k_phase1(const float* __restrict__ x,
                                                float* __restrict__ ps,   // [500][2][1000]
                                                const int* __restrict__ ei,
                                                int E, int TE,
                                                int* __restrict__ deg) {
    int b = blockIdx.x, tid = threadIdx.x;
    if (b < BN_BLOCKS) {
        int c4 = tid;
        if (c4 >= 250) return;
        int r0 = b * 200;
        float4 s = make_float4(0.f, 0.f, 0.f, 0.f);
        float4 q = make_float4(0.f, 0.f, 0.f, 0.f);
        const char* base = (const char*)x + (size_t)r0 * (D_IN * 4) + (size_t)c4 * 16;
        for (int i = 0; i < 200; i += 8) {
            float4 v[8];
            #pragma unroll
            for (int j = 0; j < 8; ++j)
                v[j] = *(const float4*)(base + (size_t)(i + j) * (D_IN * 4));
            #pragma unroll
            for (int j = 0; j < 8; ++j) {
                s.x += v[j].x; s.y += v[j].y; s.z += v[j].z; s.w += v[j].w;
                q.x += v[j].x * v[j].x; q.y += v[j].y * v[j].y;
                q.z += v[j].z * v[j].z; q.w += v[j].w * v[j].w;
            }
        }
        *(float4*)(ps + (size_t)b * 2000 + c4 * 4) = s;
        *(float4*)(ps + (size_t)b * 2000 + 1000 + c4 * 4) = q;
    } else {
        int eid = (b - BN_BLOCKS) * 256 + tid;
        if (eid >= TE) return;
        int dst = (eid < E) ? ei[E + eid] : (eid - E);
        atomicAdd(&deg[dst], 1);
    }
}

// ===== reduce partials -> cs/cs2 (40 blocks: 4 col-groups x 10 part-chunks) =====
__global__ void k_reduce(const float* __restrict__ ps,
                         float* __restrict__ cs, float* __restrict__ cs2) {
    int cg = blockIdx.x & 3;
    int ch = blockIdx.x >> 2;      // 0..9
    int c = cg * 256 + threadIdx.x;
    if (c >= D_IN) return;
    int b0 = ch * (NPART / 10), b1 = b0 + (NPART / 10);
    float s = 0.f, s2 = 0.f;
    #pragma unroll 5
    for (int b = b0; b < b1; ++b) {
        s  += ps[(size_t)b * 2000 + c];
        s2 += ps[(size_t)b * 2000 + 1000 + c];
    }
    atomicAdd(&cs[c], s);
    atomicAdd(&cs2[c], s2);
}

// ===== phase2: scan_a (blocks [0,NCH)) ∪ weight prep (rest) =====
__global__ void k_phase2(const int* __restrict__ deg, int* __restrict__ csum,
                         const float* __restrict__ W1, const float* __restrict__ W2,
                         const float* __restrict__ cs, const float* __restrict__ cs2,
                         const float* __restrict__ gamma, const float* __restrict__ beta,
                         short* __restrict__ W1t, short* __restrict__ W2t,
                         float* __restrict__ c1) {
    __shared__ int red[4];
    __shared__ float part[4][64];
    int b = blockIdx.x, tid = threadIdx.x;
    if (b < NCH) {
        int i0 = b * SCAN_CHUNK + tid * 2;
        int a = (i0 < N_NODES) ? deg[i0] : 0;
        int bb = (i0 + 1 < N_NODES) ? deg[i0 + 1] : 0;
        int t = a + bb;
        #pragma unroll
        for (int d = 1; d < 64; d <<= 1) t += __shfl_xor(t, d);
        if ((tid & 63) == 0) red[tid >> 6] = t;
        __syncthreads();
        if (tid == 0) csum[b] = red[0] + red[1] + red[2] + red[3];
        return;
    }
    int pb = b - NCH;
    if (pb < 256) {
        int idx = pb * 256 + tid;                 // 64*KPAD = 65536
        int n = idx >> 10, k = idx & (KPAD - 1);
        float v = 0.f;
        if (k < D_IN) {
            float mu  = cs[k]  * (1.f / N_NODES);
            float var = cs2[k] * (1.f / N_NODES) - mu * mu;
            float sc  = rsqrtf(var + kBnEps) * gamma[k];
            v = W1[k * 64 + n] * sc;
        }
        W1t[idx] = (short)f2bf(v);
    } else if (pb < 296) {
        int idx = (pb - 256) * 256 + tid;         // 160*64 = 10240
        if (idx < 160 * 64) {
            int n = idx >> 6, k = idx & 63;
            W2t[idx] = (short)f2bf(W2[k * 160 + n]);
        }
    } else {
        int j  = tid & 63;
        int kc = tid >> 6;
        float acc = 0.f;
        for (int k = kc * 250; k < (kc + 1) * 250; ++k) {
            float mu  = cs[k]  * (1.f / N_NODES);
            float var = cs2[k] * (1.f / N_NODES) - mu * mu;
            float sc  = rsqrtf(var + kBnEps) * gamma[k];
            float sh  = beta[k] - mu * sc;
            acc += sh * W1[k * 64 + j];
        }
        part[kc][j] = acc;
        __syncthreads();
        if (kc == 0) c1[j] = part[0][j] + part[1][j] + part[2][j] + part[3][j];
    }
}

// ===== phase3: scan_c (chunk base self-computed) =====
__global__ void k_scan_c(const int* __restrict__ deg, const int* __restrict__ csum,
                         int TE, int* __restrict__ row_start, int* __restrict__ cursor) {
    __shared__ int wsum1[4];
    __shared__ int wsum2[4];
    __shared__ int base_sh;
    int c = blockIdx.x, tid = threadIdx.x;
    int lane = tid & 63, w = tid >> 6;

    int pv = (tid < c) ? csum[tid] : 0;   // NCH <= 256
    #pragma unroll
    for (int d = 1; d < 64; d <<= 1) pv += __shfl_xor(pv, d);
    if (lane == 0) wsum1[w] = pv;
    __syncthreads();
    if (tid == 0) base_sh = wsum1[0] + wsum1[1] + wsum1[2] + wsum1[3];

    int i0 = c * SCAN_CHUNK + tid * 2;
    int a = (i0 < N_NODES) ? deg[i0] : 0;
    int b = (i0 + 1 < N_NODES) ? deg[i0 + 1] : 0;
    int t = a + b;
    int incl = t;
    #pragma unroll
    for (int d = 1; d < 64; d <<= 1) {
        int v = __shfl_up(incl, d);
        if (lane >= d) incl += v;
    }
    if (lane == 63) wsum2[w] = incl;
    __syncthreads();
    int wbase = 0;
    for (int k = 0; k < w; ++k) wbase += wsum2[k];
    int ex = base_sh + wbase + incl - t;
    if (i0 < N_NODES)     { row_start[i0] = ex;         cursor[i0] = ex; }
    if (i0 + 1 < N_NODES) { row_start[i0 + 1] = ex + a; cursor[i0 + 1] = ex + a; }
    if (c == 0 && tid == 0) row_start[N_NODES] = TE;
}

// ===== phase4: gemm1+att1 (blocks [0,G1_BLOCKS)) ∪ CSR fill (rest) =====
__global__ __launch_bounds__(256) void k_phase4(const float* __restrict__ x,
                                                const short* __restrict__ W1t,
                                                const float* __restrict__ c1,
                                                const float* __restrict__ a_src1,
                                                const float* __restrict__ a_dst1,
                                                short* __restrict__ h1b,
                                                float* __restrict__ als,
                                                float* __restrict__ ald,
                                                const int* __restrict__ ei,
                                                int E, int TE,
                                                int* __restrict__ cursor,
                                                int* __restrict__ srcs) {
    __shared__ short lA[BM * BK];
    __shared__ short lB[BN * BK];

    int tid = threadIdx.x;
    if ((int)blockIdx.x >= G1_BLOCKS) {
        int eid = ((int)blockIdx.x - G1_BLOCKS) * 256 + tid;
        if (eid < TE) {
            int src, dst;
            if (eid < E) { src = ei[eid]; dst = ei[E + eid]; }
            else { src = eid - E; dst = src; }
            int pos = atomicAdd(&cursor[dst], 1);
            srcs[pos] = src;
        }
        return;
    }

    int lane = tid & 63;
    int wave = tid >> 6;
    int l15  = lane & 15, kq = lane >> 4;
    int row0 = blockIdx.x * BM;
    int wm0  = wave * 32;

    f32x4 zero4 = {0.f, 0.f, 0.f, 0.f};
    f32x4 acc[2][4];
    #pragma unroll
    for (int m = 0; m < 2; ++m)
        #pragma unroll
        for (int n = 0; n < 4; ++n) acc[m][n] = zero4;

    int ar = tid >> 4;
    int akf4 = tid & 15;

    for (int kt = 0; kt < KTILES; ++kt) {
        int k0 = kt * BK;
        bool kok = (k0 + akf4 * 4) < D_IN;
        #pragma unroll
        for (int p = 0; p < 8; ++p) {
            int r = ar + p * 16;
            int gr = row0 + r;
            float4 v = make_float4(0.f, 0.f, 0.f, 0.f);
            if (gr < N_NODES && kok)
                v = *(const float4*)(x + (size_t)gr * D_IN + k0 + akf4 * 4);
            unsigned lo = f2bf(v.x) | ((unsigned)f2bf(v.y) << 16);
            unsigned hi = f2bf(v.z) | ((unsigned)f2bf(v.w) << 16);
            int off = r * 128 + ((((akf4 >> 1) ^ (r & 7)) << 4) | ((akf4 & 1) << 3));
            *(uint2*)((char*)lA + off) = make_uint2(lo, hi);
        }
        #pragma unroll
        for (int c = tid; c < 512; c += 256) {
            int n = c >> 3, s = c & 7;
            short8 v = *(const short8*)((const char*)W1t + n * (KPAD * 2) + k0 * 2 + (s << 4));
            int off = n * 128 + ((s ^ (n & 7)) << 4);
            *(short8*)((char*)lB + off) = v;
        }
        __syncthreads();
        #pragma unroll
        for (int h = 0; h < 2; ++h) {
            short8 aF[2], bF[4];
            #pragma unroll
            for (int m = 0; m < 2; ++m) {
                int row = wm0 + m * 16 + l15;
                int off = row * 128 + (((((h << 2) + kq)) ^ (row & 7)) << 4);
                aF[m] = *(const short8*)((const char*)lA + off);
            }
            #pragma unroll
            for (int n = 0; n < 4; ++n) {
                int col = n * 16 + l15;
                int off = col * 128 + (((((h << 2) + kq)) ^ (col & 7)) << 4);
                bF[n] = *(const short8*)((const char*)lB + off);
            }
            #pragma unroll
            for (int m = 0; m < 2; ++m)
                #pragma unroll
                for (int n = 0; n < 4; ++n)
                    acc[m][n] = __builtin_amdgcn_mfma_f32_16x16x32_bf16(aF[m], bF[n], acc[m][n], 0, 0, 0);
        }
        __syncthreads();
    }

    float cv[4];
    #pragma unroll
    for (int n = 0; n < 4; ++n) cv[n] = c1[n * 16 + l15];
    #pragma unroll
    for (int m = 0; m < 2; ++m)
        #pragma unroll
        for (int q = 0; q < 4; ++q) {
            int rl = wm0 + m * 16 + (kq << 2) + q;
            #pragma unroll
            for (int n = 0; n < 4; ++n)
                lA[rl * 64 + n * 16 + l15] = (short)f2bf(acc[m][n][q] + cv[n]);
        }
    __syncthreads();
    #pragma unroll
    for (int idx = tid; idx < 1024; idx += 256) {
        int r = idx >> 3, s = idx & 7;
        int gr = row0 + r;
        if (gr < N_NODES)
            *(short8*)((char*)h1b + (size_t)gr * 128 + (s << 4)) =
                *(const short8*)((const char*)lA + r * 128 + (s << 4));
    }
    #pragma unroll
    for (int pair = tid; pair < 1024; pair += 256) {
        int r = pair >> 3, hd = pair & 7;
        int gr = row0 + r;
        if (gr >= N_NODES) continue;
        short8 v = *(const short8*)((const char*)lA + r * 128 + hd * 16);
        float s = 0.f, d = 0.f;
        #pragma unroll
        for (int c = 0; c < 8; ++c) {
            float f = bf2f(v[c]);
            s += f * a_src1[hd * 8 + c];
            d += f * a_dst1[hd * 8 + c];
        }
        als[gr * 8 + hd] = s;
        ald[gr * 8 + hd] = d;
    }
}

// ====== FUSED layer-2 front: gather1 -> LDS -> gemm2 -> att2 logits, h2b out ======
__global__ __launch_bounds__(512) void k_fused_l2(const int* __restrict__ row_start,
                                                  const int* __restrict__ srcs,
                                                  const float* __restrict__ als1,
                                                  const float* __restrict__ ald1,
                                                  const short* __restrict__ h1b,
                                                  const float* __restrict__ b1,
                                                  const short* __restrict__ W2t,
                                                  const float* __restrict__ a_src2,
                                                  const float* __restrict__ a_dst2,
                                                  short* __restrict__ h2b,
                                                  float* __restrict__ als2,
                                                  float* __restrict__ ald2) {
    __shared__ __align__(16) char smem[40960];
    short* lA  = (short*)smem;            // [128][64] swizzled bf16 out1 tile (16 KB)
    short* lB  = (short*)(smem + 16384);  // [160][64] swizzled W2t (20 KB)
    short* stg = (short*)smem;            // [128][160] bf16 h2 tile (40 KB), reused

    int tid  = threadIdx.x;
    int lane = tid & 63;
    int wave = tid >> 6;
    int l15  = lane & 15, kq = lane >> 4;
    int row0 = blockIdx.x * 128;
    int wm0  = wave * 16;

    for (int idx = tid; idx < 1280; idx += 512) {
        int n = idx >> 3, s = idx & 7;
        short8 v = *(const short8*)((const char*)W2t + n * 128 + (s << 4));
        int off = n * 128 + ((s ^ (n & 7)) << 4);
        *(short8*)((char*)lB + off) = v;
    }

    #pragma unroll
    for (int pp = 0; pp < 2; ++pp) {
        int pair = tid + pp * 512;
        int r = pair >> 3, hd = pair & 7;
        int dst = row0 + r;
        short8 o = {0, 0, 0, 0, 0, 0, 0, 0};
        if (dst < N_NODES) {
            int beg = row_start[dst], end = row_start[dst + 1];
            float ad = ald1[dst * 8 + hd];
            float sum = 0.f;
            float acc[C_ONE] = {};
            for (int e = beg; e < end; ++e) {
                int s = srcs[e];
                float v = als1[s * 8 + hd] + ad;
                v = v >= 0.f ? v : kSlope * v;
                float wgt = __expf(v);
                short8 hv = *(const short8*)((const char*)h1b + (size_t)s * 128 + hd * 16);
                sum += wgt;
                #pragma unroll
                for (int c = 0; c < C_ONE; ++c) acc[c] += wgt * bf2f(hv[c]);
            }
            float inv = 1.f / (sum + 1e-16f);
            #pragma unroll
            for (int c = 0; c < C_ONE; ++c) {
                float v = acc[c] * inv + b1[hd * 8 + c];
                v = v > 0.f ? v : __expf(v) - 1.f;
                o[c] = (short)f2bf(v);
            }
        }
        int off = r * 128 + ((hd ^ (r & 7)) << 4);
        *(short8*)((char*)lA + off) = o;
    }
    __syncthreads();

    f32x4 zero4 = {0.f, 0.f, 0.f, 0.f};
    f32x4 acc2[10];
    #pragma unroll
    for (int n = 0; n < 10; ++n) acc2[n] = zero4;

    #pragma unroll
    for (int hh = 0; hh < 2; ++hh) {
        short8 aF, bF[10];
        {
            int row = wm0 + l15;
            int off = row * 128 + ((((hh << 2) + kq) ^ (row & 7)) << 4);
            aF = *(const short8*)((const char*)lA + off);
        }
        #pragma unroll
        for (int n = 0; n < 10; ++n) {
            int col = n * 16 + l15;
            int off = col * 128 + ((((hh << 2) + kq) ^ (col & 7)) << 4);
            bF[n] = *(const short8*)((const char*)lB + off);
        }
        #pragma unroll
        for (int n = 0; n < 10; ++n)
            acc2[n] = __builtin_amdgcn_mfma_f32_16x16x32_bf16(aF, bF[n], acc2[n], 0, 0, 0);
    }
    __syncthreads();

    #pragma unroll
    for (int q = 0; q < 4; ++q) {
        int rl = wm0 + (kq << 2) + q;
        #pragma unroll
        for (int n = 0; n < 10; ++n)
            stg[rl * 160 + n * 16 + l15] = (short)f2bf(acc2[n][q]);
    }
    __syncthreads();

    for (int pair = tid; pair < 1024; pair += 512) {
        int r = pair >> 3, hd = pair & 7;
        int dst = row0 + r;
        if (dst >= N_NODES) continue;
        const char* hp = (const char*)stg + r * 320 + hd * 40;
        float s = 0.f, d = 0.f;
        #pragma unroll
        for (int p = 0; p < 5; ++p) {
            sh4 v = *(const sh4*)(hp + p * 8);
            #pragma unroll
            for (int j = 0; j < 4; ++j) {
                float f = bf2f(v[j]);
                s += f * a_src2[hd * 20 + p * 4 + j];
                d += f * a_dst2[hd * 20 + p * 4 + j];
            }
        }
        als2[dst * 8 + hd] = s;
        ald2[dst * 8 + hd] = d;
    }
    for (int idx = tid; idx < 2560; idx += 512) {
        int r = idx / 20, c8 = idx % 20;
        int gr = row0 + r;
        if (gr < N_NODES)
            *(short8*)((char*)h2b + (size_t)gr * 320 + (c8 << 4)) =
                *(const short8*)((const char*)stg + r * 320 + (c8 << 4));
    }
}

// ====== layer-2 gather: 2-way edge split, max-free softmax, head-mean, log_softmax ======
__global__ __launch_bounds__(256) void k_gather2(const int* __restrict__ row_start,
                                                 const int* __restrict__ srcs,
                                                 const float* __restrict__ als,
                                                 const float* __restrict__ ald,
                                                 const short* __restrict__ h2,
                                                 const float* __restrict__ b2,
                                                 float* __restrict__ out) {
    int idx = blockIdx.x * blockDim.x + threadIdx.x;
    if (idx >= N_NODES * 16) return;
    int dst  = idx >> 4;
    int sub  = idx & 15;
    int hd   = sub >> 1;
    int half = sub & 1;
    int beg0 = row_start[dst], end0 = row_start[dst + 1];
    int mid  = beg0 + ((end0 - beg0 + 1) >> 1);
    int beg  = half ? mid : beg0;
    int end  = half ? end0 : mid;
    float ad = ald[dst * 8 + hd];
    float sum = 0.f;
    float acc[D_OUT] = {};
    for (int e = beg; e < end; ++e) {
        int s = srcs[e];
        float v = als[s * 8 + hd] + ad;
        v = v >= 0.f ? v : kSlope * v;
        float wgt = __expf(v);
        const char* hp = (const char*)h2 + (size_t)s * 320 + hd * 40;
        sum += wgt;
        #pragma unroll
        for (int p = 0; p < 5; ++p) {
            sh4 t = *(const sh4*)(hp + p * 8);
            #pragma unroll
            for (int j = 0; j < 4; ++j) acc[p * 4 + j] += wgt * bf2f(t[j]);
        }
    }
    sum += __shfl_xor(sum, 1);
    float inv = 1.f / (sum + 1e-16f);
    #pragma unroll
    for (int c = 0; c < D_OUT; ++c) {
        float v = acc[c];
        v += __shfl_xor(v, 1);
        v *= inv;
        v += __shfl_xor(v, 2);
        v += __shfl_xor(v, 4);
        v += __shfl_xor(v, 8);
        acc[c] = v;
    }
    if (sub == 0) {
        float vals[D_OUT];
        float mx = -1e30f;
        #pragma unroll
        for (int c = 0; c < D_OUT; ++c) {
            vals[c] = 0.125f * acc[c] + b2[c];
            mx = fmaxf(mx, vals[c]);
        }
        float s = 0.f;
        #pragma unroll
        for (int c = 0; c < D_OUT; ++c) s += __expf(vals[c] - mx);
        float lse = mx + __logf(s);
        float* op = out + (size_t)dst * D_OUT;
        #pragma unroll
        for (int c = 0; c < D_OUT; ++c) op[c] = vals[c] - lse;
    }
}

extern "C" void kernel_launch(void* const* d_in, const int* in_sizes, int n_in,
                              void* d_out, int out_size, void* d_ws, size_t ws_size,
                              hipStream_t stream) {
    const float* x      = (const float*)d_in[0];
    const int*   ei     = (const int*)d_in[1];
    const float* gamma  = (const float*)d_in[2];
    const float* beta   = (const float*)d_in[3];
    const float* W1     = (const float*)d_in[4];
    const float* a_src1 = (const float*)d_in[5];
    const float* a_dst1 = (const float*)d_in[6];
    const float* b1     = (const float*)d_in[7];
    const float* W2     = (const float*)d_in[8];
    const float* a_src2 = (const float*)d_in[9];
    const float* a_dst2 = (const float*)d_in[10];
    const float* b2     = (const float*)d_in[11];
    float* out = (float*)d_out;
    (void)n_in; (void)out_size; (void)ws_size;

    const int E  = in_sizes[1] / 2;
    const int TE = E + N_NODES;

    char* wsb = (char*)d_ws;
    size_t off = 0;
    auto alloc = [&](size_t bytes) -> void* {
        void* p = wsb + off;
        off += (bytes + 255) & ~(size_t)255;
        return p;
    };
    float* cs    = (float*)alloc(D_IN * sizeof(float));   // adjacent to cs2 (one memset)
    float* cs2   = (float*)alloc(D_IN * sizeof(float));
    float* ps    = (float*)alloc((size_t)NPART * 2000 * sizeof(float));  // 4 MB partials
    short* W1t   = (short*)alloc((size_t)64 * KPAD * sizeof(short));
    short* W2t   = (short*)alloc((size_t)160 * 64 * sizeof(short));
    float* c1    = (float*)alloc(64 * sizeof(float));
    short* h1b   = (short*)alloc((size_t)N_NODES * 64 * sizeof(short));
    short* h2b   = (short*)alloc((size_t)N_NODES * 160 * sizeof(short));
    float* als   = (float*)alloc((size_t)N_NODES * N_HEAD * sizeof(float));
    float* ald   = (float*)alloc((size_t)N_NODES * N_HEAD * sizeof(float));
    float* als2  = (float*)alloc((size_t)N_NODES * N_HEAD * sizeof(float));
    float* ald2  = (float*)alloc((size_t)N_NODES * N_HEAD * sizeof(float));
    int*   deg   = (int*)alloc((size_t)N_NODES * sizeof(int));
    int*   rs    = (int*)alloc((size_t)(N_NODES + 1) * sizeof(int));
    int*   cur   = (int*)alloc((size_t)N_NODES * sizeof(int));
    int*   csum  = (int*)alloc((size_t)NCH * sizeof(int));
    int*   srcs  = (int*)alloc((size_t)TE * sizeof(int));

    int egrid = (TE + 255) / 256;

    hipMemsetAsync(deg, 0, (size_t)N_NODES * sizeof(int), stream);
    hipMemsetAsync(cs, 0, 8192, stream);

    // phase1: BN partial stats (atomic-free) ∪ degree histogram
    k_phase1<<<BN_BLOCKS + egrid, 256, 0, stream>>>(x, ps, ei, E, TE, deg);

    // reduce partials -> cs/cs2
    k_reduce<<<40, 256, 0, stream>>>(ps, cs, cs2);

    // phase2: scan_a ∪ weight prep (BN finalize inline)
    k_phase2<<<NCH + PREP_BLOCKS, 256, 0, stream>>>(deg, csum, W1, W2, cs, cs2,
                                                     gamma, beta, W1t, W2t, c1);

    // phase3: row_start/cursor
    k_scan_c<<<NCH, 256, 0, stream>>>(deg, csum, TE, rs, cur);

    // phase4: gemm1+att1 ∪ CSR fill
    k_phase4<<<G1_BLOCKS + egrid, 256, 0, stream>>>(x, W1t, c1, a_src1, a_dst1,
                                                     h1b, als, ald, ei, E, TE, cur, srcs);

    // fused gather1 + gemm2 + att2 logits
    k_fused_l2<<<(N_NODES + 127) / 128, 512, 0, stream>>>(rs, srcs, als, ald, h1b, b1,
                                                           W2t, a_src2, a_dst2,
                                                           h2b, als2, ald2);

    // layer-2 gather + output (2-way edge split)
    k_gather2<<<(N_NODES * 16 + 255) / 256, 256, 0, stream>>>(rs, srcs, als2, ald2,
                                                               h2b, b2, out);
}